// Round 16
// baseline (773.978 us; speedup 1.0000x reference)
//
#include <hip/hip_runtime.h>

#define B_  1024
#define T_  128
#define V_  89
#define H_  256
#define NB2 256
#define NPAIR 91136          // B_*V_

typedef __attribute__((ext_vector_type(8))) short bf16x8;
typedef __attribute__((ext_vector_type(4))) float f32x4;
typedef __attribute__((ext_vector_type(4))) unsigned short u16x4;
typedef __attribute__((ext_vector_type(8))) int i32x8;
typedef __attribute__((ext_vector_type(4))) int i32x4;

__device__ __forceinline__ short f2bs(float f){
    unsigned u = __float_as_uint(f);
    unsigned r = (u + 0x7FFFu + ((u>>16)&1u)) >> 16;
    return (short)r;
}
__device__ __forceinline__ float s2f(unsigned short s){
    return __uint_as_float(((unsigned)s) << 16);
}
__device__ __forceinline__ float sig_(float x){ return 1.f/(1.f+__expf(-x)); }
__device__ __forceinline__ float tanh_(float x){ return 2.f/(1.f+__expf(-2.f*x)) - 1.f; }
__device__ __forceinline__ void bar_lgkm(){
    asm volatile("s_waitcnt lgkmcnt(0)" ::: "memory");
    __builtin_amdgcn_s_barrier();
}

// ---------------------------------------------------------------- W_hh fp32 -> fp8 [768][256]
__global__ __launch_bounds__(256) void k_cvt_fp8(
    const float* __restrict__ src, unsigned char* __restrict__ dst, int n)
{
    int i = blockIdx.x*256 + threadIdx.x;
    if (i*4 >= n) return;
    float f0 = src[i*4+0], f1 = src[i*4+1], f2 = src[i*4+2], f3 = src[i*4+3];
    int w = __builtin_amdgcn_cvt_pk_fp8_f32(f0, f1, 0, false);
    w     = __builtin_amdgcn_cvt_pk_fp8_f32(f2, f3, w, true);
    ((int*)dst)[i] = w;
}

// ---------------------------------------------------------------- W_ih -> fp8 LDS-order frags
__global__ __launch_bounds__(256) void k_prep_wihT(
    const float* __restrict__ W_ih, unsigned char* __restrict__ dst)
{
    int i = blockIdx.x*256 + threadIdx.x;
    if (i >= 18432) return;
    int l15 = i & 15; int u = i >> 4;
    int g8 = u & 3; u >>= 2;
    int kt = u % 6; u /= 6;
    int cs = u & 15; int g = u >> 4;
    int n = g*256 + cs*16 + l15;
    float f[8];
    #pragma unroll
    for (int j = 0; j < 8; ++j) {
        int k = kt*32 + g8*8 + j;
        f[j] = (k < 178) ? W_ih[(size_t)n*178 + k] : 0.f;
    }
    int w0 = __builtin_amdgcn_cvt_pk_fp8_f32(f[0], f[1], 0, false);
    w0     = __builtin_amdgcn_cvt_pk_fp8_f32(f[2], f[3], w0, true);
    int w1 = __builtin_amdgcn_cvt_pk_fp8_f32(f[4], f[5], 0, false);
    w1     = __builtin_amdgcn_cvt_pk_fp8_f32(f[6], f[7], w1, true);
    ((int*)dst)[i*2]   = w0;
    ((int*)dst)[i*2+1] = w1;
}

// ---------------------------------------------------------------- W_h -> bf16 frag-major
__global__ __launch_bounds__(256) void k_prep_whpT(
    const float* __restrict__ W_h, short* __restrict__ dst)
{
    int i = blockIdx.x*256 + threadIdx.x;
    if (i >= 3072) return;
    int l15 = i & 15; int u = i >> 4;
    int g8 = u & 3; u >>= 2;
    int kt = u % 3; int cs = u / 3;
    int cg = cs*16 + l15;
    short v[8];
    #pragma unroll
    for (int j = 0; j < 8; ++j) {
        int k = kt*32 + g8*8 + j;
        v[j] = (k < V_) ? f2bs(W_h[(size_t)cg*V_ + k]) : (short)0;
    }
    #pragma unroll
    for (int j = 0; j < 8; ++j) dst[(size_t)i*8 + j] = v[j];
}

// ---------------------------------------------------------------- coarse ffill scan: 32-t segments
__global__ __launch_bounds__(256) void k_scan_seg(
    const float* __restrict__ x, const float* __restrict__ mask,
    float* __restrict__ segVal, unsigned char* __restrict__ segHas)
{
    int gid = blockIdx.x*256 + threadIdx.x;      // 4*NPAIR = 364544 exact (1424 blocks)
    int s = gid / NPAIR, pair = gid - s*NPAIR;
    int b = pair / V_, v = pair - b*V_;
    float val = 0.f; int has = 0;
    for (int j = 31; j >= 0; --j) {
        size_t idx = ((size_t)b*T_ + s*32 + j)*V_ + v;
        if (mask[idx] > 0.f) { val = x[idx]; has = 1; break; }
    }
    segVal[(size_t)s*NPAIR + pair] = val;
    segHas[(size_t)s*NPAIR + pair] = (unsigned char)has;
}

// ---------------------------------------------------------------- k_gates2: impute+gates+gamma
// grid (256, TC/32) x 512 thr. Block = 4 batch rows x 32 t (8 phases). W_ih fp8 resident in LDS.
__global__ __launch_bounds__(512) void k_gates2(
    const float* __restrict__ x, const float* __restrict__ mask,
    const float* __restrict__ deltas, const float* __restrict__ meanset,
    const float* __restrict__ W_x, const float* __restrict__ b_x,
    const float* __restrict__ segVal, const unsigned char* __restrict__ segHas,
    const unsigned char* __restrict__ wihT, const short* __restrict__ whpT,
    const float* __restrict__ b_ih, const float* __restrict__ b_h,
    float* __restrict__ ximp, float* __restrict__ numpart, float* __restrict__ denpart,
    unsigned short* __restrict__ gi4, int t0)
{
    __shared__ unsigned char wih_lds[147456] __attribute__((aligned(16)));
    __shared__ unsigned char xl[16*200] __attribute__((aligned(16)));
    __shared__ short dl2[16*104] __attribute__((aligned(16)));
    __shared__ float wrn[4][8], wrd[4][8];

    int tid = threadIdx.x, lane = tid & 63, wv = tid >> 6;
    int l15 = lane & 15, g8 = lane >> 4;
    int bg = blockIdx.x, by = blockIdx.y;
    int tb0 = t0 + by*32;

    {
        const i32x4* wsrc = (const i32x4*)wihT;
        i32x4* wdst = (i32x4*)wih_lds;
        for (int i = tid; i < 9216; i += 512) wdst[i] = wsrc[i];
    }
    for (int i = tid; i < 16*14; i += 512) {
        int r = i/14, k = 178 + (i - r*14);
        xl[r*200 + k] = 0;
    }
    for (int i = tid; i < 16*15; i += 512) {
        int r = i/15, k = 89 + (i - r*15);
        dl2[r*104 + k] = 0;
    }

    float bir[2], biz[2], bin[2], bga[2];
    #pragma unroll
    for (int s = 0; s < 2; ++s) {
        int col = (wv + s*8)*16 + l15;
        bir[s] = b_ih[col]; biz[s] = b_ih[256 + col]; bin[s] = b_ih[512 + col];
        bga[s] = b_h[col];
    }

    bool own = tid < 4*V_;
    int bl = tid / V_, v_o = tid - bl*V_;
    int b_o = bg*4 + bl;
    int pair = b_o*V_ + v_o;
    float wxd = 0.f, bx = 0.f, mnv = 0.f, lastv = 0.f;
    float xv[4], mv[4], dv[4];
    if (own) {
        wxd = W_x[v_o*V_ + v_o]; bx = b_x[v_o]; mnv = meanset[v_o];
        int seg0 = tb0 >> 5;
        for (int s2 = 0; s2 < seg0; ++s2)
            if (segHas[(size_t)s2*NPAIR + pair]) lastv = segVal[(size_t)s2*NPAIR + pair];
        size_t base = ((size_t)b_o*T_ + tb0)*V_ + v_o;
        #pragma unroll
        for (int lt = 0; lt < 4; ++lt) {
            xv[lt] = x[base + lt*V_]; mv[lt] = mask[base + lt*V_]; dv[lt] = deltas[base + lt*V_];
        }
    }

    const long* wL = (const long*)wih_lds;
    const bf16x8* wG = (const bf16x8*)whpT;

    for (int p = 0; p < 8; ++p) {
        int tg = tb0 + p*4;
        float ln[4] = {0.f,0.f,0.f,0.f}, ld[4] = {0.f,0.f,0.f,0.f};
        if (own) {
            size_t base = ((size_t)b_o*T_ + tg)*V_ + v_o;
            #pragma unroll
            for (int lt = 0; lt < 4; ++lt) {
                float xt = xv[lt], m = mv[lt], d = dv[lt];
                float gx = __expf(-fmaxf(fmaf(d, wxd, bx), 0.f));
                lastv = (m > 0.f) ? xt : lastv;
                float xu = gx*lastv + (1.f-gx)*mnv;
                float xh = m*xt + (1.f-m)*xu;
                ximp[base + lt*V_] = xh;
                int mr = bl*4 + lt;
                int pk = __builtin_amdgcn_cvt_pk_fp8_f32(xh, m, 0, false);
                xl[mr*200 + v_o]      = (unsigned char)(pk & 0xFF);
                xl[mr*200 + V_ + v_o] = (unsigned char)((pk >> 8) & 0xFF);
                dl2[mr*104 + v_o]     = f2bs(d);
                ln[lt] = fabsf(xt - xu)*m;
                ld[lt] = m;
            }
        }
        #pragma unroll
        for (int lt = 0; lt < 4; ++lt) {
            for (int off = 32; off; off >>= 1) {
                ln[lt] += __shfl_down(ln[lt], off);
                ld[lt] += __shfl_down(ld[lt], off);
            }
        }
        if (lane == 0)
            #pragma unroll
            for (int lt = 0; lt < 4; ++lt) { wrn[lt][wv] = ln[lt]; wrd[lt][wv] = ld[lt]; }
        bar_lgkm();
        if (tid < 4) {
            float n = 0.f, d2 = 0.f;
            #pragma unroll
            for (int w = 0; w < 8; ++w) { n += wrn[tid][w]; d2 += wrd[tid][w]; }
            numpart[(size_t)(tg + tid)*NB2 + bg] = n;
            denpart[(size_t)(tg + tid)*NB2 + bg] = d2;
        }
        if (own && p < 7) {
            size_t base = ((size_t)b_o*T_ + tg + 4)*V_ + v_o;
            #pragma unroll
            for (int lt = 0; lt < 4; ++lt) {
                xv[lt] = x[base + lt*V_]; mv[lt] = mask[base + lt*V_]; dv[lt] = deltas[base + lt*V_];
            }
        }
        #pragma unroll
        for (int s = 0; s < 2; ++s) {
            int cset = wv + s*8;
            f32x4 ar = {bir[s],bir[s],bir[s],bir[s]};
            f32x4 az = {biz[s],biz[s],biz[s],biz[s]};
            f32x4 an = {bin[s],bin[s],bin[s],bin[s]};
            f32x4 ga = {bga[s],bga[s],bga[s],bga[s]};
            #pragma unroll
            for (int kt = 0; kt < 6; ++kt) {
                long a = *(const long*)&xl[l15*200 + kt*32 + g8*8];
                long br = wL[((((0*16+cset)*6+kt)*4+g8)*16) + l15];
                long bz = wL[((((1*16+cset)*6+kt)*4+g8)*16) + l15];
                long bn = wL[((((2*16+cset)*6+kt)*4+g8)*16) + l15];
                ar = __builtin_amdgcn_mfma_f32_16x16x32_fp8_fp8(a, br, ar, 0,0,0);
                az = __builtin_amdgcn_mfma_f32_16x16x32_fp8_fp8(a, bz, az, 0,0,0);
                an = __builtin_amdgcn_mfma_f32_16x16x32_fp8_fp8(a, bn, an, 0,0,0);
            }
            #pragma unroll
            for (int kt = 0; kt < 3; ++kt) {
                bf16x8 da = *(const bf16x8*)&dl2[l15*104 + kt*32 + g8*8];
                bf16x8 gw = wG[((cset*3+kt)*4+g8)*16 + l15];
                ga = __builtin_amdgcn_mfma_f32_16x16x32_bf16(da, gw, ga, 0,0,0);
            }
            int cg = cset*16 + l15;
            #pragma unroll
            for (int rr = 0; rr < 4; ++rr) {
                int ltc = by*32 + p*4 + rr;
                u16x4 v;
                v[0] = (unsigned short)f2bs(ar[rr]);
                v[1] = (unsigned short)f2bs(az[rr]);
                v[2] = (unsigned short)f2bs(an[rr]);
                v[3] = (unsigned short)f2bs(__expf(-fmaxf(ga[rr], 0.f)));
                ((u16x4*)gi4)[(((size_t)ltc*256 + bg)*4 + g8)*256 + cg] = v;
            }
        }
        bar_lgkm();
    }
}

// ---------------------------------------------------------------- k_recur: FULL-M, 16 batch rows/block
// grid 64 x 512 thr (8 waves). Lane (wv,l15,g8) owns cols c0=wv*16+l15, c1=c0+128
// for batch rows blk*16 + g8*4 + rr (rr=0..3). M=16 fully used (no replication).
__global__ __launch_bounds__(512) void k_recur(
    const unsigned short* __restrict__ gi4, const unsigned char* __restrict__ whh8,
    const float* __restrict__ b_hh, const float* __restrict__ W_cls,
    const float* __restrict__ b_cls,
    float* __restrict__ hstate, float* __restrict__ yout, float* __restrict__ yscore,
    int TC, int first, int last)
{
    __shared__ unsigned char whL[256*256];
    __shared__ unsigned char hlds[2][16*272] __attribute__((aligned(16)));
    __shared__ float yred[16][8];

    int tid = threadIdx.x, lane = tid & 63, wv = tid >> 6;  // wv 0..7
    int l15 = lane & 15, g8 = lane >> 4;
    int blk = blockIdx.x;                                    // 0..63
    int c0 = wv*16 + l15, c1 = c0 + 128;

    // stage r-gate weights swizzled (rows 0..255 of whh8)
    for (int it = 0; it < 16; ++it) {
        int idx = it*512 + tid;
        int row = idx >> 5, j = idx & 31;
        long v = *(const long*)(whh8 + (size_t)row*256 + j*8);
        *(long*)&whL[row*256 + ((j*8) ^ ((row & 15) << 4))] = v;
    }
    // z,n register-resident for both cols (64 VGPR), pinned
    i32x8 wz0[2], wn0[2], wz1[2], wn1[2];
    #pragma unroll
    for (int k2 = 0; k2 < 2; ++k2) {
        wz0[k2] = *(const i32x8*)(whh8 + (size_t)(256 + c0)*256 + k2*128 + g8*32);
        wn0[k2] = *(const i32x8*)(whh8 + (size_t)(512 + c0)*256 + k2*128 + g8*32);
        wz1[k2] = *(const i32x8*)(whh8 + (size_t)(256 + c1)*256 + k2*128 + g8*32);
        wn1[k2] = *(const i32x8*)(whh8 + (size_t)(512 + c1)*256 + k2*128 + g8*32);
    }
    #pragma unroll
    for (int k2 = 0; k2 < 2; ++k2)
        #pragma unroll
        for (int j = 0; j < 8; ++j) {
            asm volatile("" : "+v"(wz0[k2][j]));
            asm volatile("" : "+v"(wn0[k2][j]));
            asm volatile("" : "+v"(wz1[k2][j]));
            asm volatile("" : "+v"(wn1[k2][j]));
        }
    float bhr0 = b_hh[c0], bhz0 = b_hh[256 + c0], bhn0 = b_hh[512 + c0];
    float bhr1 = b_hh[c1], bhz1 = b_hh[256 + c1], bhn1 = b_hh[512 + c1];

    float h[2][4];
    #pragma unroll
    for (int rr = 0; rr < 4; ++rr) {
        int br = blk*16 + g8*4 + rr;
        h[0][rr] = first ? 0.f : hstate[(size_t)br*H_ + c0];
        h[1][rr] = first ? 0.f : hstate[(size_t)br*H_ + c1];
    }
    __syncthreads();   // whL staged

    const u16x4* gp = (const u16x4*)gi4;
#define GIDX(LT,RR,CC) ((((size_t)(LT)*256 + (blk*4 + g8))*4 + (RR))*256 + (CC))
    u16x4 ga[2][4], gb[2][4];
    #pragma unroll
    for (int rr = 0; rr < 4; ++rr) {
        ga[0][rr] = gp[GIDX(0, rr, c0)];
        ga[1][rr] = gp[GIDX(0, rr, c1)];
        gb[0][rr] = (TC > 1) ? gp[GIDX(1, rr, c0)] : ga[0][rr];
        gb[1][rr] = (TC > 1) ? gp[GIDX(1, rr, c1)] : ga[1][rr];
    }
    int sw = l15 << 4;
    const unsigned char* wb0 = &whL[(size_t)c0*256];
    const unsigned char* wb1 = &whL[(size_t)c1*256];

    for (int lt = 0; lt < TC; ++lt) {
        int cb = lt & 1;
        float hd[2][4];
        #pragma unroll
        for (int rr = 0; rr < 4; ++rr) {
            hd[0][rr] = h[0][rr] * s2f(ga[0][rr][3]);
            hd[1][rr] = h[1][rr] * s2f(ga[1][rr][3]);
            int pk = __builtin_amdgcn_cvt_pk_fp8_f32(hd[0][rr], hd[1][rr], 0, false);
            hlds[cb][(g8*4+rr)*272 + c0] = (unsigned char)(pk & 0xFF);
            hlds[cb][(g8*4+rr)*272 + c1] = (unsigned char)((pk >> 8) & 0xFF);
        }
        __syncthreads();
        // prefetch lt+2 (static regs)
        u16x4 gc[2][4];
        #pragma unroll
        for (int rr = 0; rr < 4; ++rr) {
            gc[0][rr] = (lt + 2 < TC) ? gp[GIDX(lt+2, rr, c0)] : ga[0][rr];
            gc[1][rr] = (lt + 2 < TC) ? gp[GIDX(lt+2, rr, c1)] : ga[1][rr];
        }
        // A fragments: rows = l15 (16 distinct batch rows)
        i32x8 A[2];
        #pragma unroll
        for (int k2 = 0; k2 < 2; ++k2) {
            const unsigned char* ap = &hlds[cb][l15*272 + k2*128 + g8*32];
            i32x4 lo = *(const i32x4*)(ap);
            i32x4 hi = *(const i32x4*)(ap + 16);
            i32x8 a; a[0]=lo[0]; a[1]=lo[1]; a[2]=lo[2]; a[3]=lo[3];
                     a[4]=hi[0]; a[5]=hi[1]; a[6]=hi[2]; a[7]=hi[3];
            A[k2] = a;
        }
        f32x4 sr0 = {bhr0,bhr0,bhr0,bhr0};
        f32x4 sz0 = {bhz0,bhz0,bhz0,bhz0};
        f32x4 sn0 = {bhn0,bhn0,bhn0,bhn0};
        f32x4 sr1 = {bhr1,bhr1,bhr1,bhr1};
        f32x4 sz1 = {bhz1,bhz1,bhz1,bhz1};
        f32x4 sn1 = {bhn1,bhn1,bhn1,bhn1};
        __builtin_amdgcn_s_setprio(1);
        #pragma unroll
        for (int k2 = 0; k2 < 2; ++k2) {
            int ob = k2*128 + g8*32;
            i32x4 bl0 = *(const i32x4*)(wb0 + ((ob     ) ^ sw));
            i32x4 bh0 = *(const i32x4*)(wb0 + ((ob + 16) ^ sw));
            i32x8 b0; b0[0]=bl0[0]; b0[1]=bl0[1]; b0[2]=bl0[2]; b0[3]=bl0[3];
                      b0[4]=bh0[0]; b0[5]=bh0[1]; b0[6]=bh0[2]; b0[7]=bh0[3];
            i32x4 bl1 = *(const i32x4*)(wb1 + ((ob     ) ^ sw));
            i32x4 bh1 = *(const i32x4*)(wb1 + ((ob + 16) ^ sw));
            i32x8 b1; b1[0]=bl1[0]; b1[1]=bl1[1]; b1[2]=bl1[2]; b1[3]=bl1[3];
                      b1[4]=bh1[0]; b1[5]=bh1[1]; b1[6]=bh1[2]; b1[7]=bh1[3];
            sr0 = __builtin_amdgcn_mfma_scale_f32_16x16x128_f8f6f4(A[k2], b0,      sr0, 0,0, 0,0x7F7F7F7F, 0,0x7F7F7F7F);
            sz0 = __builtin_amdgcn_mfma_scale_f32_16x16x128_f8f6f4(A[k2], wz0[k2], sz0, 0,0, 0,0x7F7F7F7F, 0,0x7F7F7F7F);
            sn0 = __builtin_amdgcn_mfma_scale_f32_16x16x128_f8f6f4(A[k2], wn0[k2], sn0, 0,0, 0,0x7F7F7F7F, 0,0x7F7F7F7F);
            sr1 = __builtin_amdgcn_mfma_scale_f32_16x16x128_f8f6f4(A[k2], b1,      sr1, 0,0, 0,0x7F7F7F7F, 0,0x7F7F7F7F);
            sz1 = __builtin_amdgcn_mfma_scale_f32_16x16x128_f8f6f4(A[k2], wz1[k2], sz1, 0,0, 0,0x7F7F7F7F, 0,0x7F7F7F7F);
            sn1 = __builtin_amdgcn_mfma_scale_f32_16x16x128_f8f6f4(A[k2], wn1[k2], sn1, 0,0, 0,0x7F7F7F7F, 0,0x7F7F7F7F);
        }
        __builtin_amdgcn_s_setprio(0);
        #pragma unroll
        for (int rr = 0; rr < 4; ++rr) {
            float rg0 = sig_(s2f(ga[0][rr][0]) + sr0[rr]);
            float zg0 = sig_(s2f(ga[0][rr][1]) + sz0[rr]);
            float ng0 = tanh_(s2f(ga[0][rr][2]) + rg0*sn0[rr]);
            h[0][rr] = (1.f - zg0)*ng0 + zg0*hd[0][rr];
            float rg1 = sig_(s2f(ga[1][rr][0]) + sr1[rr]);
            float zg1 = sig_(s2f(ga[1][rr][1]) + sz1[rr]);
            float ng1 = tanh_(s2f(ga[1][rr][2]) + rg1*sn1[rr]);
            h[1][rr] = (1.f - zg1)*ng1 + zg1*hd[1][rr];
        }
        #pragma unroll
        for (int rr = 0; rr < 4; ++rr) {
            ga[0][rr] = gb[0][rr]; ga[1][rr] = gb[1][rr];
            gb[0][rr] = gc[0][rr]; gb[1][rr] = gc[1][rr];
        }
    }
#undef GIDX

    #pragma unroll
    for (int rr = 0; rr < 4; ++rr) {
        int br = blk*16 + g8*4 + rr;
        hstate[(size_t)br*H_ + c0] = h[0][rr];
        hstate[(size_t)br*H_ + c1] = h[1][rr];
    }
    if (last) {
        float wc0 = W_cls[c0], wc1 = W_cls[c1];
        #pragma unroll
        for (int rr = 0; rr < 4; ++rr) {
            float pr = h[0][rr]*wc0 + h[1][rr]*wc1;
            pr += __shfl_xor(pr, 1);
            pr += __shfl_xor(pr, 2);
            pr += __shfl_xor(pr, 4);
            pr += __shfl_xor(pr, 8);
            if (l15 == 0) yred[g8*4 + rr][wv] = pr;
        }
        __syncthreads();
        if (tid < 16) {
            float sacc = b_cls[0];
            #pragma unroll
            for (int ww = 0; ww < 8; ++ww) sacc += yred[tid][ww];
            yout[blk*16 + tid]   = sacc;
            yscore[blk*16 + tid] = 1.f/(1.f+__expf(-sacc));
        }
    }
}

// ---------------------------------------------------------------- loss stage 1
__global__ __launch_bounds__(256) void k_loss_t(
    const float* __restrict__ numpart, const float* __restrict__ denpart,
    float* __restrict__ tpart)
{
    int t = blockIdx.x, tid = threadIdx.x;
    float n = numpart[(size_t)t*NB2 + tid];
    float d = denpart[(size_t)t*NB2 + tid];
    for (int off = 32; off; off >>= 1) { n += __shfl_down(n, off); d += __shfl_down(d, off); }
    __shared__ float sn[4], sd[4];
    int lane = tid & 63, wid = tid >> 6;
    if (lane == 0) { sn[wid] = n; sd[wid] = d; }
    __syncthreads();
    if (tid == 0) {
        float nn = sn[0]+sn[1]+sn[2]+sn[3], dd = sd[0]+sd[1]+sd[2]+sd[3];
        tpart[t] = nn / (dd + 1e-5f);
    }
}

// ---------------------------------------------------------------- loss stage 2
__global__ __launch_bounds__(128) void k_loss_final(
    const float* __restrict__ tpart, float* __restrict__ out_loss)
{
    int tid = threadIdx.x;
    float s = tpart[tid];
    for (int off = 32; off; off >>= 1) s += __shfl_down(s, off);
    __shared__ float sp[2];
    if ((tid&63)==0) sp[tid>>6] = s;
    __syncthreads();
    if (tid==0) out_loss[0] = sp[0] + sp[1];
}

static inline size_t al256(size_t x){ return (x + 255) & ~(size_t)255; }

extern "C" void kernel_launch(void* const* d_in, const int* in_sizes, int n_in,
                              void* d_out, int out_size, void* d_ws, size_t ws_size,
                              hipStream_t stream)
{
    const float* x      = (const float*)d_in[0];
    const float* mask   = (const float*)d_in[1];
    const float* deltas = (const float*)d_in[2];
    const float* meanset= (const float*)d_in[3];
    const float* W_h    = (const float*)d_in[4];
    const float* b_h    = (const float*)d_in[5];
    const float* W_x    = (const float*)d_in[6];
    const float* b_x    = (const float*)d_in[7];
    const float* W_ih   = (const float*)d_in[8];
    const float* b_ih   = (const float*)d_in[9];
    const float* W_hh   = (const float*)d_in[10];
    const float* b_hh   = (const float*)d_in[11];
    const float* W_cls  = (const float*)d_in[12];
    const float* b_cls  = (const float*)d_in[13];

    float* out    = (float*)d_out;
    float* ximp   = out;                        // B*T*V
    float* xloss  = out + (size_t)B_*T_*V_;     // 1
    float* yout   = xloss + 1;                  // B
    float* yscore = yout + B_;                  // B

    size_t off = 0;
    size_t off_whh8 = off; off = al256(off + (size_t)768*256);
    size_t off_wihT = off; off = al256(off + (size_t)18432*8);
    size_t off_whpT = off; off = al256(off + (size_t)3072*16);
    size_t off_sv   = off; off = al256(off + (size_t)4*NPAIR*4);
    size_t off_sh   = off; off = al256(off + (size_t)4*NPAIR);
    size_t off_h    = off; off = al256(off + (size_t)B_*H_*4);
    size_t off_np   = off; off = al256(off + (size_t)T_*NB2*4);
    size_t off_dp   = off; off = al256(off + (size_t)T_*NB2*4);
    size_t off_tp   = off; off = al256(off + (size_t)T_*4);
    size_t off_gi4  = off;

    int tcShift = -1;
    for (int s = 7; s >= 5; --s) {
        size_t gib = (size_t)(1 << s) * 256 * 4 * 256 * 8;  // TC * bg * g8 * col * 8B
        if (off_gi4 + gib <= ws_size) { tcShift = s; break; }
    }
    if (tcShift < 0) return;
    int TC = 1 << tcShift;
    int NC = T_ / TC;

    char* ws = (char*)d_ws;
    unsigned char* whh8 = (unsigned char*)(ws + off_whh8);
    unsigned char* wihT = (unsigned char*)(ws + off_wihT);
    short* whpT   = (short*)(ws + off_whpT);
    float* segVal = (float*)(ws + off_sv);
    unsigned char* segHas = (unsigned char*)(ws + off_sh);
    float* hstate = (float*)(ws + off_h);
    float* numpart= (float*)(ws + off_np);
    float* denpart= (float*)(ws + off_dp);
    float* tpart  = (float*)(ws + off_tp);
    unsigned short* gi4 = (unsigned short*)(ws + off_gi4);

    hipLaunchKernelGGL(k_cvt_fp8, dim3((768*256/4+255)/256), dim3(256), 0, stream, W_hh, whh8, 768*256);
    hipLaunchKernelGGL(k_prep_wihT, dim3((18432+255)/256), dim3(256), 0, stream, W_ih, wihT);
    hipLaunchKernelGGL(k_prep_whpT, dim3((3072+255)/256), dim3(256), 0, stream, W_h, whpT);
    hipLaunchKernelGGL(k_scan_seg, dim3(1424), dim3(256), 0, stream, x, mask, segVal, segHas);

    for (int ci = 0; ci < NC; ++ci) {
        int t0 = ci * TC;
        hipLaunchKernelGGL(k_gates2, dim3(256, TC/32), dim3(512), 0, stream,
                           x, mask, deltas, meanset, W_x, b_x, segVal, segHas,
                           wihT, whpT, b_ih, b_h, ximp, numpart, denpart, gi4, t0);
        hipLaunchKernelGGL(k_recur, dim3(64), dim3(512), 0, stream,
                           gi4, whh8, b_hh, W_cls, b_cls,
                           hstate, yout, yscore, TC, ci==0, ci==NC-1);
    }
    hipLaunchKernelGGL(k_loss_t, dim3(T_), dim3(256), 0, stream, numpart, denpart, tpart);
    hipLaunchKernelGGL(k_loss_final, dim3(1), dim3(128), 0, stream, tpart, xloss);
}

// Round 17
// 305.188 us; speedup vs baseline: 2.5361x; 2.5361x over previous
//
#include <hip/hip_runtime.h>

#define B_  1024
#define T_  128
#define V_  89
#define H_  256
#define NB2 256
#define NPAIR 91136          // B_*V_

typedef __attribute__((ext_vector_type(8))) short bf16x8;
typedef __attribute__((ext_vector_type(4))) float f32x4;
typedef __attribute__((ext_vector_type(4))) unsigned short u16x4;
typedef __attribute__((ext_vector_type(8))) int i32x8;
typedef __attribute__((ext_vector_type(4))) int i32x4;

__device__ __forceinline__ short f2bs(float f){
    unsigned u = __float_as_uint(f);
    unsigned r = (u + 0x7FFFu + ((u>>16)&1u)) >> 16;
    return (short)r;
}
__device__ __forceinline__ float s2f(unsigned short s){
    return __uint_as_float(((unsigned)s) << 16);
}
__device__ __forceinline__ float sig_(float x){ return 1.f/(1.f+__expf(-x)); }
__device__ __forceinline__ float tanh_(float x){ return 2.f/(1.f+__expf(-2.f*x)) - 1.f; }
__device__ __forceinline__ void bar_lgkm(){
    asm volatile("s_waitcnt lgkmcnt(0)" ::: "memory");
    __builtin_amdgcn_s_barrier();
}

// ---------------------------------------------------------------- W_hh fp32 -> fp8 [768][256]
__global__ __launch_bounds__(256) void k_cvt_fp8(
    const float* __restrict__ src, unsigned char* __restrict__ dst, int n)
{
    int i = blockIdx.x*256 + threadIdx.x;
    if (i*4 >= n) return;
    float f0 = src[i*4+0], f1 = src[i*4+1], f2 = src[i*4+2], f3 = src[i*4+3];
    int w = __builtin_amdgcn_cvt_pk_fp8_f32(f0, f1, 0, false);
    w     = __builtin_amdgcn_cvt_pk_fp8_f32(f2, f3, w, true);
    ((int*)dst)[i] = w;
}

// ---------------------------------------------------------------- W_ih -> fp8 LDS-order frags
__global__ __launch_bounds__(256) void k_prep_wihT(
    const float* __restrict__ W_ih, unsigned char* __restrict__ dst)
{
    int i = blockIdx.x*256 + threadIdx.x;
    if (i >= 18432) return;
    int l15 = i & 15; int u = i >> 4;
    int g8 = u & 3; u >>= 2;
    int kt = u % 6; u /= 6;
    int cs = u & 15; int g = u >> 4;
    int n = g*256 + cs*16 + l15;
    float f[8];
    #pragma unroll
    for (int j = 0; j < 8; ++j) {
        int k = kt*32 + g8*8 + j;
        f[j] = (k < 178) ? W_ih[(size_t)n*178 + k] : 0.f;
    }
    int w0 = __builtin_amdgcn_cvt_pk_fp8_f32(f[0], f[1], 0, false);
    w0     = __builtin_amdgcn_cvt_pk_fp8_f32(f[2], f[3], w0, true);
    int w1 = __builtin_amdgcn_cvt_pk_fp8_f32(f[4], f[5], 0, false);
    w1     = __builtin_amdgcn_cvt_pk_fp8_f32(f[6], f[7], w1, true);
    ((int*)dst)[i*2]   = w0;
    ((int*)dst)[i*2+1] = w1;
}

// ---------------------------------------------------------------- W_h -> bf16 frag-major
__global__ __launch_bounds__(256) void k_prep_whpT(
    const float* __restrict__ W_h, short* __restrict__ dst)
{
    int i = blockIdx.x*256 + threadIdx.x;
    if (i >= 3072) return;
    int l15 = i & 15; int u = i >> 4;
    int g8 = u & 3; u >>= 2;
    int kt = u % 3; int cs = u / 3;
    int cg = cs*16 + l15;
    short v[8];
    #pragma unroll
    for (int j = 0; j < 8; ++j) {
        int k = kt*32 + g8*8 + j;
        v[j] = (k < V_) ? f2bs(W_h[(size_t)cg*V_ + k]) : (short)0;
    }
    #pragma unroll
    for (int j = 0; j < 8; ++j) dst[(size_t)i*8 + j] = v[j];
}

// ---------------------------------------------------------------- coarse ffill scan: 32-t segments
__global__ __launch_bounds__(256) void k_scan_seg(
    const float* __restrict__ x, const float* __restrict__ mask,
    float* __restrict__ segVal, unsigned char* __restrict__ segHas)
{
    int gid = blockIdx.x*256 + threadIdx.x;      // 4*NPAIR = 364544 exact (1424 blocks)
    int s = gid / NPAIR, pair = gid - s*NPAIR;
    int b = pair / V_, v = pair - b*V_;
    float val = 0.f; int has = 0;
    for (int j = 31; j >= 0; --j) {
        size_t idx = ((size_t)b*T_ + s*32 + j)*V_ + v;
        if (mask[idx] > 0.f) { val = x[idx]; has = 1; break; }
    }
    segVal[(size_t)s*NPAIR + pair] = val;
    segHas[(size_t)s*NPAIR + pair] = (unsigned char)has;
}

// ---------------------------------------------------------------- k_gates2: impute+gates+gamma
// grid (256, TC/32) x 512 thr. Block = 4 batch rows x 32 t (8 phases). W_ih fp8 resident in LDS.
__global__ __launch_bounds__(512) void k_gates2(
    const float* __restrict__ x, const float* __restrict__ mask,
    const float* __restrict__ deltas, const float* __restrict__ meanset,
    const float* __restrict__ W_x, const float* __restrict__ b_x,
    const float* __restrict__ segVal, const unsigned char* __restrict__ segHas,
    const unsigned char* __restrict__ wihT, const short* __restrict__ whpT,
    const float* __restrict__ b_ih, const float* __restrict__ b_h,
    float* __restrict__ ximp, float* __restrict__ numpart, float* __restrict__ denpart,
    unsigned short* __restrict__ gi4, int t0)
{
    __shared__ unsigned char wih_lds[147456] __attribute__((aligned(16)));
    __shared__ unsigned char xl[16*200] __attribute__((aligned(16)));
    __shared__ short dl2[16*104] __attribute__((aligned(16)));
    __shared__ float wrn[4][8], wrd[4][8];

    int tid = threadIdx.x, lane = tid & 63, wv = tid >> 6;
    int l15 = lane & 15, g8 = lane >> 4;
    int bg = blockIdx.x, by = blockIdx.y;
    int tb0 = t0 + by*32;

    {
        const i32x4* wsrc = (const i32x4*)wihT;
        i32x4* wdst = (i32x4*)wih_lds;
        for (int i = tid; i < 9216; i += 512) wdst[i] = wsrc[i];
    }
    for (int i = tid; i < 16*14; i += 512) {
        int r = i/14, k = 178 + (i - r*14);
        xl[r*200 + k] = 0;
    }
    for (int i = tid; i < 16*15; i += 512) {
        int r = i/15, k = 89 + (i - r*15);
        dl2[r*104 + k] = 0;
    }

    float bir[2], biz[2], bin[2], bga[2];
    #pragma unroll
    for (int s = 0; s < 2; ++s) {
        int col = (wv + s*8)*16 + l15;
        bir[s] = b_ih[col]; biz[s] = b_ih[256 + col]; bin[s] = b_ih[512 + col];
        bga[s] = b_h[col];
    }

    bool own = tid < 4*V_;
    int bl = tid / V_, v_o = tid - bl*V_;
    int b_o = bg*4 + bl;
    int pair = b_o*V_ + v_o;
    float wxd = 0.f, bx = 0.f, mnv = 0.f, lastv = 0.f;
    float xv[4], mv[4], dv[4];
    if (own) {
        wxd = W_x[v_o*V_ + v_o]; bx = b_x[v_o]; mnv = meanset[v_o];
        int seg0 = tb0 >> 5;
        for (int s2 = 0; s2 < seg0; ++s2)
            if (segHas[(size_t)s2*NPAIR + pair]) lastv = segVal[(size_t)s2*NPAIR + pair];
        size_t base = ((size_t)b_o*T_ + tb0)*V_ + v_o;
        #pragma unroll
        for (int lt = 0; lt < 4; ++lt) {
            xv[lt] = x[base + lt*V_]; mv[lt] = mask[base + lt*V_]; dv[lt] = deltas[base + lt*V_];
        }
    }

    const long* wL = (const long*)wih_lds;
    const bf16x8* wG = (const bf16x8*)whpT;

    for (int p = 0; p < 8; ++p) {
        int tg = tb0 + p*4;
        float ln[4] = {0.f,0.f,0.f,0.f}, ld[4] = {0.f,0.f,0.f,0.f};
        if (own) {
            size_t base = ((size_t)b_o*T_ + tg)*V_ + v_o;
            #pragma unroll
            for (int lt = 0; lt < 4; ++lt) {
                float xt = xv[lt], m = mv[lt], d = dv[lt];
                float gx = __expf(-fmaxf(fmaf(d, wxd, bx), 0.f));
                lastv = (m > 0.f) ? xt : lastv;
                float xu = gx*lastv + (1.f-gx)*mnv;
                float xh = m*xt + (1.f-m)*xu;
                ximp[base + lt*V_] = xh;
                int mr = bl*4 + lt;
                int pk = __builtin_amdgcn_cvt_pk_fp8_f32(xh, m, 0, false);
                xl[mr*200 + v_o]      = (unsigned char)(pk & 0xFF);
                xl[mr*200 + V_ + v_o] = (unsigned char)((pk >> 8) & 0xFF);
                dl2[mr*104 + v_o]     = f2bs(d);
                ln[lt] = fabsf(xt - xu)*m;
                ld[lt] = m;
            }
        }
        #pragma unroll
        for (int lt = 0; lt < 4; ++lt) {
            for (int off = 32; off; off >>= 1) {
                ln[lt] += __shfl_down(ln[lt], off);
                ld[lt] += __shfl_down(ld[lt], off);
            }
        }
        if (lane == 0)
            #pragma unroll
            for (int lt = 0; lt < 4; ++lt) { wrn[lt][wv] = ln[lt]; wrd[lt][wv] = ld[lt]; }
        bar_lgkm();
        if (tid < 4) {
            float n = 0.f, d2 = 0.f;
            #pragma unroll
            for (int w = 0; w < 8; ++w) { n += wrn[tid][w]; d2 += wrd[tid][w]; }
            numpart[(size_t)(tg + tid)*NB2 + bg] = n;
            denpart[(size_t)(tg + tid)*NB2 + bg] = d2;
        }
        if (own && p < 7) {
            size_t base = ((size_t)b_o*T_ + tg + 4)*V_ + v_o;
            #pragma unroll
            for (int lt = 0; lt < 4; ++lt) {
                xv[lt] = x[base + lt*V_]; mv[lt] = mask[base + lt*V_]; dv[lt] = deltas[base + lt*V_];
            }
        }
        #pragma unroll
        for (int s = 0; s < 2; ++s) {
            int cset = wv + s*8;
            f32x4 ar = {bir[s],bir[s],bir[s],bir[s]};
            f32x4 az = {biz[s],biz[s],biz[s],biz[s]};
            f32x4 an = {bin[s],bin[s],bin[s],bin[s]};
            f32x4 ga = {bga[s],bga[s],bga[s],bga[s]};
            #pragma unroll
            for (int kt = 0; kt < 6; ++kt) {
                long a = *(const long*)&xl[l15*200 + kt*32 + g8*8];
                long br = wL[((((0*16+cset)*6+kt)*4+g8)*16) + l15];
                long bz = wL[((((1*16+cset)*6+kt)*4+g8)*16) + l15];
                long bn = wL[((((2*16+cset)*6+kt)*4+g8)*16) + l15];
                ar = __builtin_amdgcn_mfma_f32_16x16x32_fp8_fp8(a, br, ar, 0,0,0);
                az = __builtin_amdgcn_mfma_f32_16x16x32_fp8_fp8(a, bz, az, 0,0,0);
                an = __builtin_amdgcn_mfma_f32_16x16x32_fp8_fp8(a, bn, an, 0,0,0);
            }
            #pragma unroll
            for (int kt = 0; kt < 3; ++kt) {
                bf16x8 da = *(const bf16x8*)&dl2[l15*104 + kt*32 + g8*8];
                bf16x8 gw = wG[((cset*3+kt)*4+g8)*16 + l15];
                ga = __builtin_amdgcn_mfma_f32_16x16x32_bf16(da, gw, ga, 0,0,0);
            }
            int cg = cset*16 + l15;
            #pragma unroll
            for (int rr = 0; rr < 4; ++rr) {
                int ltc = by*32 + p*4 + rr;
                u16x4 v;
                v[0] = (unsigned short)f2bs(ar[rr]);
                v[1] = (unsigned short)f2bs(az[rr]);
                v[2] = (unsigned short)f2bs(an[rr]);
                v[3] = (unsigned short)f2bs(__expf(-fmaxf(ga[rr], 0.f)));
                ((u16x4*)gi4)[(((size_t)ltc*256 + bg)*4 + g8)*256 + cg] = v;
            }
        }
        bar_lgkm();
    }
}

// ---------------------------------------------------------------- k_recur: 16 waves, 1 col/lane
// (round-12 proven structure; barrier = lgkm-only so gate prefetch stays in flight)
__global__ __launch_bounds__(1024) void k_recur(
    const unsigned short* __restrict__ gi4, const unsigned char* __restrict__ whh8,
    const float* __restrict__ b_hh, const float* __restrict__ W_cls,
    const float* __restrict__ b_cls,
    float* __restrict__ hstate, float* __restrict__ yout, float* __restrict__ yscore,
    int TC, int first, int last)
{
    __shared__ unsigned char whL[256*256];
    __shared__ unsigned char hlds[2][4*272] __attribute__((aligned(16)));
    __shared__ float yred[4][16];

    int tid = threadIdx.x, lane = tid & 63, wv16 = tid >> 6;
    int l15 = lane & 15, g8 = lane >> 4;
    int blk = blockIdx.x;
    int c = wv16*16 + l15;

    #pragma unroll
    for (int it = 0; it < 8; ++it) {
        int idx = it*1024 + tid;
        int row = idx >> 5, j = idx & 31;
        long v = *(const long*)(whh8 + (size_t)row*256 + j*8);
        *(long*)&whL[row*256 + ((j*8) ^ ((row & 15) << 4))] = v;
    }
    i32x8 wz[2], wn[2];
    #pragma unroll
    for (int k2 = 0; k2 < 2; ++k2) {
        wz[k2] = *(const i32x8*)(whh8 + (size_t)(256 + c)*256 + k2*128 + g8*32);
        wn[k2] = *(const i32x8*)(whh8 + (size_t)(512 + c)*256 + k2*128 + g8*32);
    }
    #pragma unroll
    for (int k2 = 0; k2 < 2; ++k2) {
        #pragma unroll
        for (int j = 0; j < 8; ++j) {
            asm volatile("" : "+v"(wz[k2][j]));
            asm volatile("" : "+v"(wn[k2][j]));
        }
    }
    float bhr = b_hh[c], bhz = b_hh[256 + c], bhn = b_hh[512 + c];
    float h = first ? 0.f : hstate[(size_t)(blk*4 + g8)*H_ + c];
    __syncthreads();   // whL staged

    const u16x4* gp = (const u16x4*)gi4;
#define GIDX(LT) ((((size_t)(LT)*256 + blk)*4 + g8)*256 + c)
    u16x4 gv0 = gp[GIDX(0)];
    u16x4 gv1 = (TC > 1) ? gp[GIDX(1)] : gv0;
    int sw = l15 << 4;
    const unsigned char* wb = &whL[(size_t)c*256];

    for (int lt = 0; lt < TC; ++lt) {
        int cb = lt & 1;
        float hd = h * s2f(gv0[3]);
        int pk = __builtin_amdgcn_cvt_pk_fp8_f32(hd, hd, 0, false);
        hlds[cb][g8*272 + c] = (unsigned char)(pk & 0xFF);
        bar_lgkm();
        u16x4 gv2 = gv1;
        if (lt + 2 < TC) gv2 = gp[GIDX(lt + 2)];
        i32x8 A[2];
        #pragma unroll
        for (int k2 = 0; k2 < 2; ++k2) {
            const unsigned char* ap = &hlds[cb][(l15 >> 2)*272 + k2*128 + g8*32];
            i32x4 lo = *(const i32x4*)(ap);
            i32x4 hi = *(const i32x4*)(ap + 16);
            i32x8 a; a[0]=lo[0]; a[1]=lo[1]; a[2]=lo[2]; a[3]=lo[3];
                     a[4]=hi[0]; a[5]=hi[1]; a[6]=hi[2]; a[7]=hi[3];
            A[k2] = a;
        }
        f32x4 sr = {bhr,bhr,bhr,bhr};
        f32x4 sz = {bhz,bhz,bhz,bhz};
        f32x4 sn = {bhn,bhn,bhn,bhn};
        __builtin_amdgcn_s_setprio(1);
        #pragma unroll
        for (int k2 = 0; k2 < 2; ++k2) {
            int ob = k2*128 + g8*32;
            i32x4 blo = *(const i32x4*)(wb + ((ob     ) ^ sw));
            i32x4 bhi = *(const i32x4*)(wb + ((ob + 16) ^ sw));
            i32x8 b; b[0]=blo[0]; b[1]=blo[1]; b[2]=blo[2]; b[3]=blo[3];
                     b[4]=bhi[0]; b[5]=bhi[1]; b[6]=bhi[2]; b[7]=bhi[3];
            sr = __builtin_amdgcn_mfma_scale_f32_16x16x128_f8f6f4(A[k2], b,      sr, 0,0, 0,0x7F7F7F7F, 0,0x7F7F7F7F);
            sz = __builtin_amdgcn_mfma_scale_f32_16x16x128_f8f6f4(A[k2], wz[k2], sz, 0,0, 0,0x7F7F7F7F, 0,0x7F7F7F7F);
            sn = __builtin_amdgcn_mfma_scale_f32_16x16x128_f8f6f4(A[k2], wn[k2], sn, 0,0, 0,0x7F7F7F7F, 0,0x7F7F7F7F);
        }
        __builtin_amdgcn_s_setprio(0);
        float rg = sig_(s2f(gv0[0]) + sr[0]);
        float zg = sig_(s2f(gv0[1]) + sz[0]);
        float ng = tanh_(s2f(gv0[2]) + rg*sn[0]);
        h = (1.f - zg)*ng + zg*hd;
        gv0 = gv1; gv1 = gv2;
    }
#undef GIDX

    hstate[(size_t)(blk*4 + g8)*H_ + c] = h;

    if (last) {
        float pr = h * W_cls[c];
        pr += __shfl_xor(pr, 1);
        pr += __shfl_xor(pr, 2);
        pr += __shfl_xor(pr, 4);
        pr += __shfl_xor(pr, 8);
        if (l15 == 0) yred[g8][wv16] = pr;
        __syncthreads();
        if (tid < 4) {
            float sacc = b_cls[0];
            #pragma unroll
            for (int ww = 0; ww < 16; ++ww) sacc += yred[tid][ww];
            yout[blk*4 + tid]   = sacc;
            yscore[blk*4 + tid] = 1.f/(1.f+__expf(-sacc));
        }
    }
}

// ---------------------------------------------------------------- loss stage 1
__global__ __launch_bounds__(256) void k_loss_t(
    const float* __restrict__ numpart, const float* __restrict__ denpart,
    float* __restrict__ tpart)
{
    int t = blockIdx.x, tid = threadIdx.x;
    float n = numpart[(size_t)t*NB2 + tid];
    float d = denpart[(size_t)t*NB2 + tid];
    for (int off = 32; off; off >>= 1) { n += __shfl_down(n, off); d += __shfl_down(d, off); }
    __shared__ float sn[4], sd[4];
    int lane = tid & 63, wid = tid >> 6;
    if (lane == 0) { sn[wid] = n; sd[wid] = d; }
    __syncthreads();
    if (tid == 0) {
        float nn = sn[0]+sn[1]+sn[2]+sn[3], dd = sd[0]+sd[1]+sd[2]+sd[3];
        tpart[t] = nn / (dd + 1e-5f);
    }
}

// ---------------------------------------------------------------- loss stage 2
__global__ __launch_bounds__(128) void k_loss_final(
    const float* __restrict__ tpart, float* __restrict__ out_loss)
{
    int tid = threadIdx.x;
    float s = tpart[tid];
    for (int off = 32; off; off >>= 1) s += __shfl_down(s, off);
    __shared__ float sp[2];
    if ((tid&63)==0) sp[tid>>6] = s;
    __syncthreads();
    if (tid==0) out_loss[0] = sp[0] + sp[1];
}

static inline size_t al256(size_t x){ return (x + 255) & ~(size_t)255; }

extern "C" void kernel_launch(void* const* d_in, const int* in_sizes, int n_in,
                              void* d_out, int out_size, void* d_ws, size_t ws_size,
                              hipStream_t stream)
{
    const float* x      = (const float*)d_in[0];
    const float* mask   = (const float*)d_in[1];
    const float* deltas = (const float*)d_in[2];
    const float* meanset= (const float*)d_in[3];
    const float* W_h    = (const float*)d_in[4];
    const float* b_h    = (const float*)d_in[5];
    const float* W_x    = (const float*)d_in[6];
    const float* b_x    = (const float*)d_in[7];
    const float* W_ih   = (const float*)d_in[8];
    const float* b_ih   = (const float*)d_in[9];
    const float* W_hh   = (const float*)d_in[10];
    const float* b_hh   = (const float*)d_in[11];
    const float* W_cls  = (const float*)d_in[12];
    const float* b_cls  = (const float*)d_in[13];

    float* out    = (float*)d_out;
    float* ximp   = out;                        // B*T*V
    float* xloss  = out + (size_t)B_*T_*V_;     // 1
    float* yout   = xloss + 1;                  // B
    float* yscore = yout + B_;                  // B

    size_t off = 0;
    size_t off_whh8 = off; off = al256(off + (size_t)768*256);
    size_t off_wihT = off; off = al256(off + (size_t)18432*8);
    size_t off_whpT = off; off = al256(off + (size_t)3072*16);
    size_t off_sv   = off; off = al256(off + (size_t)4*NPAIR*4);
    size_t off_sh   = off; off = al256(off + (size_t)4*NPAIR);
    size_t off_h    = off; off = al256(off + (size_t)B_*H_*4);
    size_t off_np   = off; off = al256(off + (size_t)T_*NB2*4);
    size_t off_dp   = off; off = al256(off + (size_t)T_*NB2*4);
    size_t off_tp   = off; off = al256(off + (size_t)T_*4);
    size_t off_gi4  = off;

    int tcShift = -1;
    for (int s = 7; s >= 5; --s) {
        size_t gib = (size_t)(1 << s) * 256 * 4 * 256 * 8;  // TC * bg * g8 * col * 8B
        if (off_gi4 + gib <= ws_size) { tcShift = s; break; }
    }
    if (tcShift < 0) return;
    int TC = 1 << tcShift;
    int NC = T_ / TC;

    char* ws = (char*)d_ws;
    unsigned char* whh8 = (unsigned char*)(ws + off_whh8);
    unsigned char* wihT = (unsigned char*)(ws + off_wihT);
    short* whpT   = (short*)(ws + off_whpT);
    float* segVal = (float*)(ws + off_sv);
    unsigned char* segHas = (unsigned char*)(ws + off_sh);
    float* hstate = (float*)(ws + off_h);
    float* numpart= (float*)(ws + off_np);
    float* denpart= (float*)(ws + off_dp);
    float* tpart  = (float*)(ws + off_tp);
    unsigned short* gi4 = (unsigned short*)(ws + off_gi4);

    hipLaunchKernelGGL(k_cvt_fp8, dim3((768*256/4+255)/256), dim3(256), 0, stream, W_hh, whh8, 768*256);
    hipLaunchKernelGGL(k_prep_wihT, dim3((18432+255)/256), dim3(256), 0, stream, W_ih, wihT);
    hipLaunchKernelGGL(k_prep_whpT, dim3((3072+255)/256), dim3(256), 0, stream, W_h, whpT);
    hipLaunchKernelGGL(k_scan_seg, dim3(1424), dim3(256), 0, stream, x, mask, segVal, segHas);

    for (int ci = 0; ci < NC; ++ci) {
        int t0 = ci * TC;
        hipLaunchKernelGGL(k_gates2, dim3(256, TC/32), dim3(512), 0, stream,
                           x, mask, deltas, meanset, W_x, b_x, segVal, segHas,
                           wihT, whpT, b_ih, b_h, ximp, numpart, denpart, gi4, t0);
        hipLaunchKernelGGL(k_recur, dim3(256), dim3(1024), 0, stream,
                           gi4, whh8, b_hh, W_cls, b_cls,
                           hstate, yout, yscore, TC, ci==0, ci==NC-1);
    }
    hipLaunchKernelGGL(k_loss_t, dim3(T_), dim3(256), 0, stream, numpart, denpart, tpart);
    hipLaunchKernelGGL(k_loss_final, dim3(1), dim3(128), 0, stream, tpart, xloss);
}